// Round 9
// baseline (835.969 us; speedup 1.0000x reference)
//
#include <hip/hip_runtime.h>
#include <hip/hip_bf16.h>
#include <math.h>

#define Nn 8192
#define Dd 256
#define Uu 128
#define MI 16
#define NJC 16                 // j-chunks (one per block column)
#define JCL (Nn / NJC)         // 512 j per block
#define NIT (JCL / 16)         // 32 iterations of 16 j

typedef __attribute__((ext_vector_type(4))) float f32x4;
typedef __attribute__((ext_vector_type(8))) short s16x8;
typedef __attribute__((ext_vector_type(4))) short s16x4;

#define MFMA_K32(a, b, c) __builtin_amdgcn_mfma_f32_16x16x32_bf16((a), (b), (c), 0, 0, 0)

// direct-to-LDS 16B/lane copy: LDS dest = uniform base + lane*16, source per-lane
#define GL_LDS(src, dst)                                                              \
  __builtin_amdgcn_global_load_lds(                                                   \
      (const __attribute__((address_space(1))) unsigned int*)(src),                   \
      (__attribute__((address_space(3))) unsigned int*)(dst), 16, 0, 0)

// K=16 bf16 MFMA: C layout (col=l15,row=4q4+r) of the S^T MFMA == B-frag layout
// (col=l15,k=4q4+e) of this op -> P goes register-direct from S to PV.
__device__ __forceinline__ f32x4 mfma_k16(s16x4 a, s16x4 b, f32x4 c){
#if __has_builtin(__builtin_amdgcn_mfma_f32_16x16x16bf16_1k)
  return __builtin_amdgcn_mfma_f32_16x16x16bf16_1k(a, b, c, 0, 0, 0);
#else
  asm("v_mfma_f32_16x16x16_bf16 %0, %1, %2, %0" : "+v"(c) : "v"(a), "v"(b));
  return c;
#endif
}

__device__ __forceinline__ short f2bf(float f){
  unsigned int u = __float_as_uint(f);
  u += 0x7fffu + ((u >> 16) & 1u);           // RNE
  return (short)(u >> 16);
}

__device__ __forceinline__ float waveSum(float v){
  #pragma unroll
  for (int off = 32; off >= 1; off >>= 1) v += __shfl_xor(v, off);
  return v;
}

// x = expmap0(features @ kernel) -> xh (bf16 [N][U]), x2 = tanh(|z|)^2,
// v4 (V tiles in uc-granular LDS order [jb][uc][q4w][l15][e]);
// 256 threads: half-block g owns 8 rows -> serial FMA chain halved, 8 waves/CU.
__global__ __launch_bounds__(256) void k_prep(const float* __restrict__ feat,
                                              const float* __restrict__ kern,
                                              const float* __restrict__ bias,
                                              short* __restrict__ xh,
                                              short* __restrict__ v4,
                                              float* __restrict__ x2,
                                              float* __restrict__ bb){
  const int t = threadIdx.x;
  const int u = t & 127;                      // output column
  const int g = t >> 7;                       // row-half 0/1
  const int n0 = blockIdx.x * 16;
  __shared__ float fS[16][Dd];
  __shared__ float red[4][8];
  __shared__ float redb[4];
  {
    const f32x4* fg = (const f32x4*)(feat + (size_t)n0 * Dd);
    f32x4* fd = (f32x4*)fS;
    #pragma unroll
    for (int c = 0; c < 4; ++c) fd[c * 256 + t] = fg[c * 256 + t];
  }
  __syncthreads();
  float zz[8];
  #pragma unroll
  for (int r = 0; r < 8; ++r) zz[r] = 0.f;
  for (int dq = 0; dq < 64; ++dq){
    const int d = dq * 4;
    const float k0 = kern[(size_t)(d + 0) * Uu + u];
    const float k1 = kern[(size_t)(d + 1) * Uu + u];
    const float k2 = kern[(size_t)(d + 2) * Uu + u];
    const float k3 = kern[(size_t)(d + 3) * Uu + u];
    #pragma unroll
    for (int r = 0; r < 8; ++r){
      const f32x4 f4 = *(const f32x4*)&fS[g * 8 + r][d];
      zz[r] = fmaf(f4.x, k0, fmaf(f4.y, k1, fmaf(f4.z, k2, fmaf(f4.w, k3, zz[r]))));
    }
  }
  // waves 0,1 hold g=0 (rows 0-7); waves 2,3 hold g=1 (rows 8-15)
  #pragma unroll
  for (int r = 0; r < 8; ++r){
    float v = waveSum(zz[r] * zz[r]);
    if ((t & 63) == 0) red[t >> 6][r] = v;
  }
  __syncthreads();
  float scl[8];
  #pragma unroll
  for (int r = 0; r < 8; ++r){
    const float ns  = (g == 0) ? (red[0][r] + red[1][r]) : (red[2][r] + red[3][r]);
    const float nrm = fmaxf(sqrtf(ns), 1e-15f);
    const float th  = tanhf(nrm);
    scl[r] = th / nrm;
    xh[(size_t)(n0 + g * 8 + r) * Uu + u] = f2bf(zz[r] * scl[r]);
  }
  // v4 element (u, jw=4*q4w+e) at short-offset uc*256 + q4w*64 + l15*4 + e;
  // this thread owns jw = g*8 .. g*8+7 -> q4w = 2g + {0,1}
  {
    short* vt = v4 + (size_t)blockIdx.x * 2048 + (size_t)(u >> 4) * 256 + (u & 15) * 4;
    #pragma unroll
    for (int qq = 0; qq < 2; ++qq){
      s16x4 w;
      #pragma unroll
      for (int e = 0; e < 4; ++e) w[e] = f2bf(zz[qq * 4 + e] * scl[qq * 4 + e]);
      *(s16x4*)(vt + (g * 2 + qq) * 64) = w;
    }
  }
  if (t < 16){
    const float ns  = (t < 8) ? (red[0][t] + red[1][t]) : (red[2][t - 8] + red[3][t - 8]);
    const float nrm = fmaxf(sqrtf(ns), 1e-15f);
    const float th  = tanhf(nrm);
    x2[n0 + t] = th * th;
  }
  if (blockIdx.x == 0){
    const float bv = (t < 128) ? bias[t] : 0.f;
    float v = waveSum(bv * bv);
    if ((t & 63) == 0) redb[t >> 6] = v;
    __syncthreads();
    const float n2  = redb[0] + redb[1] + redb[2] + redb[3];
    const float nrm = fmaxf(sqrtf(n2), 1e-15f);
    const float th  = tanhf(nrm);
    if (t < 128) bb[t] = bv * th / nrm;
    if (t == 0) bb[Uu] = th * th;
  }
}

// LDS-shared attention, TLP-first: NJC=16 -> 2048 blocks = 8 blocks/CU (was 4).
// R2-R8 showed no pipe >42% and every in-iteration scheduling lever returning
// <5%: the kernel is LATENCY-bound at ~3 resident chains/SIMD. Doubling resident
// blocks doubles independent chains per SIMD. Body = R6-proven serial 16-j form
// (52 VGPR < the 64 cap of launch_bounds(256,8); LDS 18KB -> 8 blocks fit).
__global__ __launch_bounds__(256, 8) void k_attn(const int* __restrict__ adj,
                                                 const short* __restrict__ xh,
                                                 const short* __restrict__ v4,
                                                 const float* __restrict__ x2g,
                                                 float* __restrict__ Opart,
                                                 float* __restrict__ lpart){
  const int t    = threadIdx.x;
  const int lane = t & 63;
  const int wid  = t >> 6;
  const int l15  = lane & 15;
  const int q4   = lane >> 4;
  const int ig   = blockIdx.x >> 4;           // 128 i-groups of 64 rows
  const int jc   = blockIdx.x & 15;           // j-chunk shared by the 4 waves
  const int i0   = ig * 64 + wid * 16;
  const int irow = i0 + l15;
  const int jbase = jc * JCL;

  __shared__ __align__(16) short kb[2][2048];   // pre-fragmented K tile [kk][lane*16B]
  __shared__ __align__(16) short vb[2][2048];   // V tile [uc][q4][l15][e]
  __shared__ __align__(16) float x2S[JCL];      // x2 chunk (2KB), staged once

  // staging sources (wave wid stages fragment-chunk kk=wid of K, quarter wid of V)
  const char* ksrc = (const char*)xh + (size_t)jbase * 256
                     + (size_t)(lane & 15) * 256 + wid * 64 + (lane >> 4) * 16;
  const char* vsrc = (const char*)v4 + (size_t)jbase * 256 + wid * 1024 + lane * 16;

  // stage tile 0 + x2 chunk into LDS (earliest possible issue)
  GL_LDS(ksrc, (char*)&kb[0][0] + wid * 1024);
  GL_LDS(vsrc, (char*)&vb[0][0] + wid * 1024);
  if (wid < 2)
    GL_LDS((const char*)(x2g + jbase) + wid * 1024 + lane * 16, (char*)x2S + wid * 1024);

  // Q B-frags in registers for the whole kernel
  s16x8 qf[4];
  {
    const short* qp = xh + (size_t)irow * Uu + q4 * 8;
    #pragma unroll
    for (int kk = 0; kk < 4; ++kk) qf[kk] = *(const s16x8*)(qp + kk * 32);
  }
  const float x2i  = x2g[irow];
  const float Bv   = 1.f - x2i;
  const float Bv2j = Bv * Bv;
  const float nBv2 = -2.f * Bv;

  f32x4 oc[8];
  #pragma unroll
  for (int uc = 0; uc < 8; ++uc) oc[uc] = (f32x4){0.f, 0.f, 0.f, 0.f};
  float lacc = 0.f;

  // diagonal (j==i) only possible in one iteration of one chunk
  const int itDiag = ((i0 >> 9) == jc) ? ((i0 & 511) >> 4) : -1;

  const int* ap = adj + (size_t)irow * Nn + jbase + q4 * 4;

  // 3-deep adj register queue (16 cache lines per in-flight instruction)
  int4 aqA = *(const int4*)(ap);
  int4 aqB = *(const int4*)(ap + 16);
  int4 aqC = *(const int4*)(ap + 32);

  asm volatile("s_waitcnt vmcnt(0)" ::: "memory");
  __builtin_amdgcn_s_barrier();
  __builtin_amdgcn_sched_barrier(0);

  #pragma unroll 1
  for (int it = 0; it < NIT; ++it){
    const int cur = it & 1;
    // ---- stage next tile into the other buffer (oldest vmem ops of this iter) ----
    if (it + 1 < NIT){
      GL_LDS(ksrc + (size_t)(it + 1) * 4096, (char*)&kb[cur ^ 1][0] + wid * 1024);
      GL_LDS(vsrc + (size_t)(it + 1) * 4096, (char*)&vb[cur ^ 1][0] + wid * 1024);
    }
    __builtin_amdgcn_sched_barrier(0);
    // adj prefetch 3 iterations ahead; clamp at strip end
    const int4 aqN = *(const int4*)(ap + (((it + 3 < NIT) ? (it + 3) : (NIT - 1)) << 4));

    // ---- LDS reads: K frags 4x b128, V frags 8x b64, x2 broadcast ----
    s16x8 kf[4];
    #pragma unroll
    for (int kk = 0; kk < 4; ++kk)
      kf[kk] = *(const s16x8*)((const char*)&kb[cur][0] + kk * 1024 + lane * 16);
    s16x4 vf[8];
    #pragma unroll
    for (int uc = 0; uc < 8; ++uc)
      vf[uc] = *(const s16x4*)((const char*)&vb[cur][0] + uc * 512 + lane * 8);
    const f32x4 x2j = *(const f32x4*)&x2S[it * 16 + q4 * 4];

    // ---- S^T slice: 4 K32 MFMA, lane holds xy for (i=l15, j=j0+4q4+r) ----
    f32x4 s = {0.f, 0.f, 0.f, 0.f};
    s = MFMA_K32(kf[0], qf[0], s);
    s = MFMA_K32(kf[1], qf[1], s);
    s = MFMA_K32(kf[2], qf[2], s);
    s = MFMA_K32(kf[3], qf[3], s);

    // ---- dist -> p = exp(dist) closed form, mask, pack to bf16 B-frag ----
    const int aarr[4] = {aqA.x, aqA.y, aqA.z, aqA.w};
    const bool dg = (it == itDiag);
    const int j0 = jbase + it * 16;
    s16x4 pb;
    #pragma unroll
    for (int r = 0; r < 4; ++r){
      const float xy  = s[r];
      const float x2v = x2j[r];
      const float Aa  = fmaf(-2.f, xy, 1.f + x2v);
      const float num = fmaf(Aa * Aa, x2i, fmaf(nBv2 * Aa, xy, Bv2j * x2v));
      const float den = fmaf(x2i, x2v, fmaf(-2.f, xy, 1.f));
      const float sq  = __builtin_amdgcn_sqrtf(fmaxf(num, 0.f));
      const float pd  = fmaxf(den - sq, 1e-30f);
      float p = fminf((den + sq) * __builtin_amdgcn_rcpf(pd), 2.0e7f);
      bool keep = (aarr[r] != 0) && (sq != 0.f);
      if (dg) keep = keep && ((j0 + 4 * q4 + r) != irow);
      p = keep ? p : 0.f;
      lacc += p;
      pb[r] = f2bf(p);
    }

    // ---- O^T += V^T . P^T : 8 K16 MFMA, P direct from registers ----
    #pragma unroll
    for (int uc = 0; uc < 8; ++uc) oc[uc] = mfma_k16(vf[uc], pb, oc[uc]);

    aqA = aqB; aqB = aqC; aqC = aqN;
    // stages must land before any wave reads buf[cur^1]; the newest vmem op
    // (adj queue tail) stays in flight across the barrier
    asm volatile("s_waitcnt vmcnt(1)" ::: "memory");
    __builtin_amdgcn_s_barrier();
    __builtin_amdgcn_sched_barrier(0);
  }

  // ---- epilogue: reduce l over q4, store per-chunk partials (no atomics) ----
  lacc += __shfl_xor(lacc, 16);
  lacc += __shfl_xor(lacc, 32);
  if (lane < 16) lpart[(size_t)jc * Nn + i0 + lane] = lacc;
  float* op = Opart + ((size_t)jc * Nn + irow) * Uu + q4 * 4;
  #pragma unroll
  for (int uc = 0; uc < 8; ++uc) *(f32x4*)(op + uc * 16) = oc[uc];
}

// epilogue: sum 16 partials, normalize, mobius matvec rescale, mobius bias add
__global__ __launch_bounds__(256) void k_out(const float* __restrict__ Opart,
                                             const float* __restrict__ lpart,
                                             const float* __restrict__ x2g,
                                             const float* __restrict__ bb,
                                             float* __restrict__ out){
  const int t  = threadIdx.x;
  const int i0 = blockIdx.x * MI;
  const int er = t >> 4;
  const int ec = t & 15;
  float l = 0.f;
  #pragma unroll
  for (int c = 0; c < NJC; ++c) l += lpart[(size_t)c * Nn + i0 + er];
  const float linv = 1.f / fmaxf(l, 1e-30f);
  float mx[8]; float s2 = 0.f;
  #pragma unroll
  for (int k = 0; k < 8; ++k){
    float v = 0.f;
    #pragma unroll
    for (int c = 0; c < NJC; ++c)
      v += Opart[((size_t)c * Nn + i0 + er) * Uu + ec + 16 * k];
    v *= linv;
    mx[k] = v; s2 = fmaf(v, v, s2);
  }
  s2 += __shfl_xor(s2, 1); s2 += __shfl_xor(s2, 2);
  s2 += __shfl_xor(s2, 4); s2 += __shfl_xor(s2, 8);
  const float mx_n = fmaxf(sqrtf(s2), 1e-15f);
  const float x2e  = x2g[i0 + er];
  const float x_n  = fmaxf(sqrtf(x2e), 1e-15f);
  const float xcl  = fminf(x_n, 1.f - 1e-7f);
  const float art  = 0.5f * __logf((1.f + xcl) / (1.f - xcl));
  const float th   = tanhf(mx_n / x_n * art);
  const float rmn  = th / mx_n;
  float o[8], bu[8]; float ob = 0.f;
  #pragma unroll
  for (int k = 0; k < 8; ++k){
    bu[k] = bb[ec + 16 * k];
    o[k]  = mx[k] * rmn;
    ob = fmaf(o[k], bu[k], ob);
  }
  ob += __shfl_xor(ob, 1); ob += __shfl_xor(ob, 2);
  ob += __shfl_xor(ob, 4); ob += __shfl_xor(ob, 8);
  const float o2   = th * th;
  const float b2   = bb[Uu];
  const float cnum = 1.f + 2.f * ob + b2;
  const float cden = fmaf(o2, b2, 1.f + 2.f * ob);
  const float rden = 1.f / fmaxf(cden, 1e-15f);
  const float co   = 1.f - o2;
  #pragma unroll
  for (int k = 0; k < 8; ++k)
    out[(size_t)(i0 + er) * Uu + ec + 16 * k] = (cnum * o[k] + co * bu[k]) * rden;
}

extern "C" void kernel_launch(void* const* d_in, const int* in_sizes, int n_in,
                              void* d_out, int out_size, void* d_ws, size_t ws_size,
                              hipStream_t stream){
  (void)in_sizes; (void)n_in; (void)out_size; (void)ws_size;
  const float* feat = (const float*)d_in[0];
  const int*   adj  = (const int*)d_in[1];
  const float* kern = (const float*)d_in[2];
  const float* bias = (const float*)d_in[3];

  float* Opart = (float*)d_ws;                          // [16][N][U] f32, 64 MB
  float* lpart = Opart + (size_t)NJC * Nn * Uu;         // [16][N]
  float* x2    = lpart + (size_t)NJC * Nn;              // [N]
  float* bbw   = x2 + Nn;                               // [U+1] (padded to 132)
  short* xh    = (short*)(bbw + 132);                   // [N][U] bf16, 2 MB
  short* v4    = xh + (size_t)Nn * Uu;                  // [N/16][2048] bf16, 2 MB

  k_prep<<<Nn / 16, 256, 0, stream>>>(feat, kern, bias, xh, v4, x2, bbw);
  k_attn<<<(Nn / 64) * NJC, 256, 0, stream>>>(adj, xh, v4, x2, Opart, lpart);
  k_out <<<Nn / MI, 256, 0, stream>>>(Opart, lpart, x2, bbw, (float*)d_out);
}

// Round 10
// 498.365 us; speedup vs baseline: 1.6774x; 1.6774x over previous
//
#include <hip/hip_runtime.h>
#include <hip/hip_bf16.h>
#include <math.h>

#define Nn 8192
#define Dd 256
#define Uu 128
#define MI 16
#define NJC 8                  // j-chunks (one per block column)
#define JCL (Nn / NJC)         // 1024 j per block
#define TJ 32                  // j per iteration (2 subtiles of 16)
#define NIT (JCL / TJ)         // 32 iterations

typedef __attribute__((ext_vector_type(4))) float f32x4;
typedef __attribute__((ext_vector_type(8))) short s16x8;
typedef __attribute__((ext_vector_type(4))) short s16x4;
typedef __attribute__((ext_vector_type(4))) unsigned short u16x4;
typedef __attribute__((ext_vector_type(8))) unsigned short u16x8;

#define MFMA_K32(a, b, c) __builtin_amdgcn_mfma_f32_16x16x32_bf16((a), (b), (c), 0, 0, 0)

// direct-to-LDS 16B/lane copy: LDS dest = uniform base + lane*16, source per-lane
#define GL_LDS(src, dst)                                                              \
  __builtin_amdgcn_global_load_lds(                                                   \
      (const __attribute__((address_space(1))) unsigned int*)(src),                   \
      (__attribute__((address_space(3))) unsigned int*)(dst), 16, 0, 0)

// K=16 bf16 MFMA: C layout (col=l15,row=4q4+r) of the S^T MFMA == B-frag layout
// (col=l15,k=4q4+e) of this op -> P goes register-direct from S to PV.
__device__ __forceinline__ f32x4 mfma_k16(s16x4 a, s16x4 b, f32x4 c){
#if __has_builtin(__builtin_amdgcn_mfma_f32_16x16x16bf16_1k)
  return __builtin_amdgcn_mfma_f32_16x16x16bf16_1k(a, b, c, 0, 0, 0);
#else
  asm("v_mfma_f32_16x16x16_bf16 %0, %1, %2, %0" : "+v"(c) : "v"(a), "v"(b));
  return c;
#endif
}

__device__ __forceinline__ short f2bf(float f){
  unsigned int u = __float_as_uint(f);
  u += 0x7fffu + ((u >> 16) & 1u);           // RNE
  return (short)(u >> 16);
}

__device__ __forceinline__ float waveSum(float v){
  #pragma unroll
  for (int off = 32; off >= 1; off >>= 1) v += __shfl_xor(v, off);
  return v;
}

// adj bit-pack: adjp[itile][j] bit b = (adj[itile*16+b][j] != 0).
// Sequential streaming read of the 256MB adj (vs k_attn's former scattered 64B
// reads at ~1.5 TB/s effective); output 8MB, L2/L3-resident for k_attn.
__global__ __launch_bounds__(256) void k_pack(const int* __restrict__ adj,
                                              unsigned short* __restrict__ adjp){
  const int it4 = blockIdx.x >> 2;            // i-tile (16 rows)
  const int jc0 = (blockIdx.x & 3) << 11;     // 2048-col chunk
  const int j0  = jc0 + threadIdx.x * 8;      // 8 cols per thread
  const int* base = adj + (size_t)it4 * 16 * Nn + j0;
  unsigned short w0=0,w1=0,w2=0,w3=0,w4=0,w5=0,w6=0,w7=0;
  #pragma unroll 4
  for (int b = 0; b < 16; ++b){
    const int4 a0 = *(const int4*)(base + (size_t)b * Nn);
    const int4 a1 = *(const int4*)(base + (size_t)b * Nn + 4);
    const unsigned short m = (unsigned short)(1u << b);
    if (a0.x) w0 |= m;  if (a0.y) w1 |= m;  if (a0.z) w2 |= m;  if (a0.w) w3 |= m;
    if (a1.x) w4 |= m;  if (a1.y) w5 |= m;  if (a1.z) w6 |= m;  if (a1.w) w7 |= m;
  }
  u16x8 w; w[0]=w0; w[1]=w1; w[2]=w2; w[3]=w3; w[4]=w4; w[5]=w5; w[6]=w6; w[7]=w7;
  *(u16x8*)(adjp + (size_t)it4 * Nn + j0) = w;
}

// x = expmap0(features @ kernel) -> xh (bf16 [N][U]), x2 = tanh(|z|)^2,
// v4 (V tiles in uc-granular LDS order [jb][uc][q4w][l15][e]);
// 256 threads: half-block g owns 8 rows -> serial FMA chain halved, 8 waves/CU.
__global__ __launch_bounds__(256) void k_prep(const float* __restrict__ feat,
                                              const float* __restrict__ kern,
                                              const float* __restrict__ bias,
                                              short* __restrict__ xh,
                                              short* __restrict__ v4,
                                              float* __restrict__ x2,
                                              float* __restrict__ bb){
  const int t = threadIdx.x;
  const int u = t & 127;                      // output column
  const int g = t >> 7;                       // row-half 0/1
  const int n0 = blockIdx.x * 16;
  __shared__ float fS[16][Dd];
  __shared__ float red[4][8];
  __shared__ float redb[4];
  {
    const f32x4* fg = (const f32x4*)(feat + (size_t)n0 * Dd);
    f32x4* fd = (f32x4*)fS;
    #pragma unroll
    for (int c = 0; c < 4; ++c) fd[c * 256 + t] = fg[c * 256 + t];
  }
  __syncthreads();
  float zz[8];
  #pragma unroll
  for (int r = 0; r < 8; ++r) zz[r] = 0.f;
  for (int dq = 0; dq < 64; ++dq){
    const int d = dq * 4;
    const float k0 = kern[(size_t)(d + 0) * Uu + u];
    const float k1 = kern[(size_t)(d + 1) * Uu + u];
    const float k2 = kern[(size_t)(d + 2) * Uu + u];
    const float k3 = kern[(size_t)(d + 3) * Uu + u];
    #pragma unroll
    for (int r = 0; r < 8; ++r){
      const f32x4 f4 = *(const f32x4*)&fS[g * 8 + r][d];
      zz[r] = fmaf(f4.x, k0, fmaf(f4.y, k1, fmaf(f4.z, k2, fmaf(f4.w, k3, zz[r]))));
    }
  }
  // waves 0,1 hold g=0 (rows 0-7); waves 2,3 hold g=1 (rows 8-15)
  #pragma unroll
  for (int r = 0; r < 8; ++r){
    float v = waveSum(zz[r] * zz[r]);
    if ((t & 63) == 0) red[t >> 6][r] = v;
  }
  __syncthreads();
  float scl[8];
  #pragma unroll
  for (int r = 0; r < 8; ++r){
    const float ns  = (g == 0) ? (red[0][r] + red[1][r]) : (red[2][r] + red[3][r]);
    const float nrm = fmaxf(sqrtf(ns), 1e-15f);
    const float th  = tanhf(nrm);
    scl[r] = th / nrm;
    xh[(size_t)(n0 + g * 8 + r) * Uu + u] = f2bf(zz[r] * scl[r]);
  }
  // v4 element (u, jw=4*q4w+e) at short-offset uc*256 + q4w*64 + l15*4 + e;
  // this thread owns jw = g*8 .. g*8+7 -> q4w = 2g + {0,1}
  {
    short* vt = v4 + (size_t)blockIdx.x * 2048 + (size_t)(u >> 4) * 256 + (u & 15) * 4;
    #pragma unroll
    for (int qq = 0; qq < 2; ++qq){
      s16x4 w;
      #pragma unroll
      for (int e = 0; e < 4; ++e) w[e] = f2bf(zz[qq * 4 + e] * scl[qq * 4 + e]);
      *(s16x4*)(vt + (g * 2 + qq) * 64) = w;
    }
  }
  if (t < 16){
    const float ns  = (t < 8) ? (red[0][t] + red[1][t]) : (red[2][t - 8] + red[3][t - 8]);
    const float nrm = fmaxf(sqrtf(ns), 1e-15f);
    const float th  = tanhf(nrm);
    x2[n0 + t] = th * th;
  }
  if (blockIdx.x == 0){
    const float bv = (t < 128) ? bias[t] : 0.f;
    float v = waveSum(bv * bv);
    if ((t & 63) == 0) redb[t >> 6] = v;
    __syncthreads();
    const float n2  = redb[0] + redb[1] + redb[2] + redb[3];
    const float nrm = fmaxf(sqrtf(n2), 1e-15f);
    const float th  = tanhf(nrm);
    if (t < 128) bb[t] = bv * th / nrm;
    if (t == 0) bb[Uu] = th * th;
  }
}

// LDS-shared attention, 32-j tiles (R8-proven structure). adj now comes from the
// 8MB bit-packed adjp (L2-resident): per subtile ONE broadcast 8B ushort4 load
// per lane replaces 16 scattered 64B HBM lines -- removes the scattered-adj HBM
// efficiency wall (~1.5 TB/s effective) that was the invariant ~6000cy/16j cost.
// Per-iter vmem, pinned order: [4x gl_lds stage(t+1)] then [2x adjp u16x4 (t+2)];
// pre-barrier vmcnt(2) drains the stages, leaves the 2 adjp loads in flight.
__global__ __launch_bounds__(256, 4) void k_attn(const unsigned short* __restrict__ adjp,
                                                 const short* __restrict__ xh,
                                                 const short* __restrict__ v4,
                                                 const float* __restrict__ x2g,
                                                 float* __restrict__ Opart,
                                                 float* __restrict__ lpart){
  const int t    = threadIdx.x;
  const int lane = t & 63;
  const int wid  = t >> 6;
  const int l15  = lane & 15;
  const int q4   = lane >> 4;
  const int ig   = blockIdx.x >> 3;           // 128 i-groups of 64 rows
  const int jc   = blockIdx.x & 7;            // j-chunk shared by the 4 waves
  const int i0   = ig * 64 + wid * 16;
  const int irow = i0 + l15;
  const int jbase = jc * JCL;

  __shared__ __align__(16) short kb[2][4096];   // K tile (2 subtiles, frag layout)
  __shared__ __align__(16) short vb[2][4096];   // V tile (2 subtiles, uc layout)
  __shared__ __align__(16) float x2S[JCL];      // x2 chunk, staged once

  // per-wave staging sources (wave wid stages chunk kk=wid / quarter wid)
  const char* ksrcW = (const char*)xh + (size_t)jbase * 256
                      + l15 * 256 + wid * 64 + q4 * 16;
  const char* vsrcW = (const char*)v4 + (size_t)(jbase >> 4) * 4096
                      + wid * 1024 + lane * 16;

  // stage tile 0 (both subtiles) + x2 chunk
  GL_LDS(ksrcW,        (char*)&kb[0][0] + wid * 1024);
  GL_LDS(ksrcW + 4096, (char*)&kb[0][0] + 4096 + wid * 1024);
  GL_LDS(vsrcW,        (char*)&vb[0][0] + wid * 1024);
  GL_LDS(vsrcW + 4096, (char*)&vb[0][0] + 4096 + wid * 1024);
  GL_LDS((const char*)(x2g + jbase) + wid * 1024 + lane * 16, (char*)x2S + wid * 1024);

  // Q B-frags in registers for the whole kernel
  s16x8 qf[4];
  {
    const short* qp = xh + (size_t)irow * Uu + q4 * 8;
    #pragma unroll
    for (int kk = 0; kk < 4; ++kk) qf[kk] = *(const s16x8*)(qp + kk * 32);
  }
  const float x2i  = x2g[irow];
  const float Bv   = 1.f - x2i;
  const float Bv2j = Bv * Bv;
  const float nBv2 = -2.f * Bv;

  f32x4 oc[8];
  #pragma unroll
  for (int uc = 0; uc < 8; ++uc) oc[uc] = (f32x4){0.f, 0.f, 0.f, 0.f};
  float lacc = 0.f;

  // diagonal (j==i): one 32-j tile, one 16-j subtile of it
  const int itDiag = ((i0 >> 10) == jc) ? ((i0 & 1023) >> 5) : -1;
  const int sDiag  = (i0 >> 4) & 1;

  // packed-adj pointer for this wave's i-tile; per subtile: ushort4 at col
  // j0+q4*4 (broadcast across l15 lanes), bit l15 = keep
  const unsigned short* app = adjp + (size_t)(i0 >> 4) * Nn + jbase + q4 * 4;

  // 2-deep adjp queue of u16x4 PAIRS (subtile 0/1), loaded 2 tiles ahead
  u16x4 aqA0 = *(const u16x4*)(app);
  u16x4 aqA1 = *(const u16x4*)(app + 16);
  u16x4 aqB0 = *(const u16x4*)(app + 32);
  u16x4 aqB1 = *(const u16x4*)(app + 48);

  asm volatile("s_waitcnt vmcnt(0)" ::: "memory");
  __builtin_amdgcn_s_barrier();
  __builtin_amdgcn_sched_barrier(0);

  #pragma unroll 1
  for (int it = 0; it < NIT; ++it){
    const int cur = it & 1;
    // ---- stage tile it+1 (4 gl_lds, oldest vmem ops of this iter) ----
    if (it + 1 < NIT){
      const size_t o = (size_t)(it + 1) * 8192;
      GL_LDS(ksrcW + o,        (char*)&kb[cur ^ 1][0] + wid * 1024);
      GL_LDS(ksrcW + o + 4096, (char*)&kb[cur ^ 1][0] + 4096 + wid * 1024);
      GL_LDS(vsrcW + o,        (char*)&vb[cur ^ 1][0] + wid * 1024);
      GL_LDS(vsrcW + o + 4096, (char*)&vb[cur ^ 1][0] + 4096 + wid * 1024);
    }
    __builtin_amdgcn_sched_barrier(0);
    // ---- adjp prefetch for tile it+2 (the 2 NEWEST vmem ops; clamp at end) ----
    const int itn = (it + 2 < NIT) ? (it + 2) : (NIT - 1);
    const u16x4 aqN0 = *(const u16x4*)(app + itn * 32);
    const u16x4 aqN1 = *(const u16x4*)(app + itn * 32 + 16);
    __builtin_amdgcn_sched_barrier(0);

    // ---- two serial 16-j subtiles ----
    #pragma unroll
    for (int sdx = 0; sdx < 2; ++sdx){
      const char* kbp = (const char*)&kb[cur][0] + sdx * 4096;
      const char* vbp = (const char*)&vb[cur][0] + sdx * 4096;
      s16x8 kf[4];
      #pragma unroll
      for (int kk = 0; kk < 4; ++kk)
        kf[kk] = *(const s16x8*)(kbp + kk * 1024 + lane * 16);
      f32x4 s = {0.f, 0.f, 0.f, 0.f};
      s = MFMA_K32(kf[0], qf[0], s);
      s = MFMA_K32(kf[1], qf[1], s);
      s = MFMA_K32(kf[2], qf[2], s);
      s = MFMA_K32(kf[3], qf[3], s);

      const f32x4 x2j = *(const f32x4*)&x2S[it * TJ + sdx * 16 + q4 * 4];
      const u16x4 aq  = sdx ? aqA1 : aqA0;
      float pv[4];
      #pragma unroll
      for (int r = 0; r < 4; ++r){
        const float xy  = s[r];
        const float x2v = x2j[r];
        const float Aa  = fmaf(-2.f, xy, 1.f + x2v);
        const float num = fmaf(Aa * Aa, x2i, fmaf(nBv2 * Aa, xy, Bv2j * x2v));
        const float den = fmaf(x2i, x2v, fmaf(-2.f, xy, 1.f));
        const float sq  = __builtin_amdgcn_sqrtf(fmaxf(num, 0.f));
        const float pd  = fmaxf(den - sq, 1e-30f);
        const float p   = fminf((den + sq) * __builtin_amdgcn_rcpf(pd), 2.0e7f);
        const bool keep = (((aq[r] >> l15) & 1) != 0) && (sq != 0.f);
        pv[r] = keep ? p : 0.f;
      }
      if (it == itDiag && sdx == sDiag){      // wave-uniform branch
        const int j0 = jbase + it * TJ + sdx * 16;
        #pragma unroll
        for (int r = 0; r < 4; ++r)
          if ((j0 + 4 * q4 + r) == irow) pv[r] = 0.f;
      }
      lacc += (pv[0] + pv[1]) + (pv[2] + pv[3]);
      s16x4 pb;
      #pragma unroll
      for (int r = 0; r < 4; ++r) pb[r] = f2bf(pv[r]);

      s16x4 vf[8];
      #pragma unroll
      for (int uc = 0; uc < 8; ++uc)
        vf[uc] = *(const s16x4*)(vbp + uc * 512 + lane * 8);
      #pragma unroll
      for (int uc = 0; uc < 8; ++uc) oc[uc] = mfma_k16(vf[uc], pb, oc[uc]);
    }

    aqA0 = aqB0; aqA1 = aqB1; aqB0 = aqN0; aqB1 = aqN1;
    // drain the 4 stage gl_lds; leave the 2 adjp loads (tile it+2) in flight
    asm volatile("s_waitcnt vmcnt(2)" ::: "memory");
    __builtin_amdgcn_s_barrier();
    __builtin_amdgcn_sched_barrier(0);
  }

  // ---- epilogue: reduce l over q4, store per-chunk partials (no atomics) ----
  lacc += __shfl_xor(lacc, 16);
  lacc += __shfl_xor(lacc, 32);
  if (lane < 16) lpart[(size_t)jc * Nn + i0 + lane] = lacc;
  float* op = Opart + ((size_t)jc * Nn + irow) * Uu + q4 * 4;
  #pragma unroll
  for (int uc = 0; uc < 8; ++uc) *(f32x4*)(op + uc * 16) = oc[uc];
}

// epilogue: sum 8 partials, normalize, mobius matvec rescale, mobius bias add
__global__ __launch_bounds__(256) void k_out(const float* __restrict__ Opart,
                                             const float* __restrict__ lpart,
                                             const float* __restrict__ x2g,
                                             const float* __restrict__ bb,
                                             float* __restrict__ out){
  const int t  = threadIdx.x;
  const int i0 = blockIdx.x * MI;
  const int er = t >> 4;
  const int ec = t & 15;
  float l = 0.f;
  #pragma unroll
  for (int c = 0; c < NJC; ++c) l += lpart[(size_t)c * Nn + i0 + er];
  const float linv = 1.f / fmaxf(l, 1e-30f);
  float mx[8]; float s2 = 0.f;
  #pragma unroll
  for (int k = 0; k < 8; ++k){
    float v = 0.f;
    #pragma unroll
    for (int c = 0; c < NJC; ++c)
      v += Opart[((size_t)c * Nn + i0 + er) * Uu + ec + 16 * k];
    v *= linv;
    mx[k] = v; s2 = fmaf(v, v, s2);
  }
  s2 += __shfl_xor(s2, 1); s2 += __shfl_xor(s2, 2);
  s2 += __shfl_xor(s2, 4); s2 += __shfl_xor(s2, 8);
  const float mx_n = fmaxf(sqrtf(s2), 1e-15f);
  const float x2e  = x2g[i0 + er];
  const float x_n  = fmaxf(sqrtf(x2e), 1e-15f);
  const float xcl  = fminf(x_n, 1.f - 1e-7f);
  const float art  = 0.5f * __logf((1.f + xcl) / (1.f - xcl));
  const float th   = tanhf(mx_n / x_n * art);
  const float rmn  = th / mx_n;
  float o[8], bu[8]; float ob = 0.f;
  #pragma unroll
  for (int k = 0; k < 8; ++k){
    bu[k] = bb[ec + 16 * k];
    o[k]  = mx[k] * rmn;
    ob = fmaf(o[k], bu[k], ob);
  }
  ob += __shfl_xor(ob, 1); ob += __shfl_xor(ob, 2);
  ob += __shfl_xor(ob, 4); ob += __shfl_xor(ob, 8);
  const float o2   = th * th;
  const float b2   = bb[Uu];
  const float cnum = 1.f + 2.f * ob + b2;
  const float cden = fmaf(o2, b2, 1.f + 2.f * ob);
  const float rden = 1.f / fmaxf(cden, 1e-15f);
  const float co   = 1.f - o2;
  #pragma unroll
  for (int k = 0; k < 8; ++k)
    out[(size_t)(i0 + er) * Uu + ec + 16 * k] = (cnum * o[k] + co * bu[k]) * rden;
}

extern "C" void kernel_launch(void* const* d_in, const int* in_sizes, int n_in,
                              void* d_out, int out_size, void* d_ws, size_t ws_size,
                              hipStream_t stream){
  (void)in_sizes; (void)n_in; (void)out_size; (void)ws_size;
  const float* feat = (const float*)d_in[0];
  const int*   adj  = (const int*)d_in[1];
  const float* kern = (const float*)d_in[2];
  const float* bias = (const float*)d_in[3];

  float* Opart = (float*)d_ws;                          // [8][N][U] f32, 33.5 MB
  float* lpart = Opart + (size_t)NJC * Nn * Uu;         // [8][N]
  float* x2    = lpart + (size_t)NJC * Nn;              // [N]
  float* bbw   = x2 + Nn;                               // [U+1] (padded to 132)
  short* xh    = (short*)(bbw + 132);                   // [N][U] bf16, 2 MB
  short* v4    = xh + (size_t)Nn * Uu;                  // [N/16][2048] bf16, 2 MB
  unsigned short* adjp = (unsigned short*)(v4 + (size_t)Nn * Uu);  // [N/16][N], 8 MB

  k_pack<<<(Nn / 16) * 4, 256, 0, stream>>>(adj, adjp);
  k_prep<<<Nn / 16, 256, 0, stream>>>(feat, kern, bias, xh, v4, x2, bbw);
  k_attn<<<(Nn / 64) * NJC, 256, 0, stream>>>(adjp, xh, v4, x2, Opart, lpart);
  k_out <<<Nn / MI, 256, 0, stream>>>(Opart, lpart, x2, bbw, (float*)d_out);
}

// Round 11
// 445.928 us; speedup vs baseline: 1.8747x; 1.1176x over previous
//
#include <hip/hip_runtime.h>
#include <hip/hip_bf16.h>
#include <math.h>

#define Nn 8192
#define Dd 256
#define Uu 128
#define MI 16
#define NJC 16                 // j-chunks (one per block column)
#define JCL (Nn / NJC)         // 512 j per block
#define TJ 32                  // j per iteration (2 subtiles of 16)
#define NIT (JCL / TJ)         // 16 iterations

typedef __attribute__((ext_vector_type(4))) float f32x4;
typedef __attribute__((ext_vector_type(8))) short s16x8;
typedef __attribute__((ext_vector_type(4))) short s16x4;

#define MFMA_K32(a, b, c) __builtin_amdgcn_mfma_f32_16x16x32_bf16((a), (b), (c), 0, 0, 0)

// direct-to-LDS 16B/lane copy: LDS dest = uniform base + lane*16, source per-lane
#define GL_LDS(src, dst)                                                              \
  __builtin_amdgcn_global_load_lds(                                                   \
      (const __attribute__((address_space(1))) unsigned int*)(src),                   \
      (__attribute__((address_space(3))) unsigned int*)(dst), 16, 0, 0)

// K=16 bf16 MFMA: C layout (col=l15,row=4q4+r) of the S^T MFMA == B-frag layout
// (col=l15,k=4q4+e) of this op -> P goes register-direct from S to PV.
__device__ __forceinline__ f32x4 mfma_k16(s16x4 a, s16x4 b, f32x4 c){
#if __has_builtin(__builtin_amdgcn_mfma_f32_16x16x16bf16_1k)
  return __builtin_amdgcn_mfma_f32_16x16x16bf16_1k(a, b, c, 0, 0, 0);
#else
  asm("v_mfma_f32_16x16x16_bf16 %0, %1, %2, %0" : "+v"(c) : "v"(a), "v"(b));
  return c;
#endif
}

__device__ __forceinline__ short f2bf(float f){
  unsigned int u = __float_as_uint(f);
  u += 0x7fffu + ((u >> 16) & 1u);           // RNE
  return (short)(u >> 16);
}

__device__ __forceinline__ float waveSum(float v){
  #pragma unroll
  for (int off = 32; off >= 1; off >>= 1) v += __shfl_xor(v, off);
  return v;
}

// x = expmap0(features @ kernel) -> xh (bf16 [N][U]), x2 = tanh(|z|)^2,
// v4 (V tiles in uc-granular LDS order [jb][uc][q4w][l15][e]);
// 256 threads: half-block g owns 8 rows -> serial FMA chain halved, 8 waves/CU.
__global__ __launch_bounds__(256) void k_prep(const float* __restrict__ feat,
                                              const float* __restrict__ kern,
                                              const float* __restrict__ bias,
                                              short* __restrict__ xh,
                                              short* __restrict__ v4,
                                              float* __restrict__ x2,
                                              float* __restrict__ bb){
  const int t = threadIdx.x;
  const int u = t & 127;                      // output column
  const int g = t >> 7;                       // row-half 0/1
  const int n0 = blockIdx.x * 16;
  __shared__ float fS[16][Dd];
  __shared__ float red[4][8];
  __shared__ float redb[4];
  {
    const f32x4* fg = (const f32x4*)(feat + (size_t)n0 * Dd);
    f32x4* fd = (f32x4*)fS;
    #pragma unroll
    for (int c = 0; c < 4; ++c) fd[c * 256 + t] = fg[c * 256 + t];
  }
  __syncthreads();
  float zz[8];
  #pragma unroll
  for (int r = 0; r < 8; ++r) zz[r] = 0.f;
  for (int dq = 0; dq < 64; ++dq){
    const int d = dq * 4;
    const float k0 = kern[(size_t)(d + 0) * Uu + u];
    const float k1 = kern[(size_t)(d + 1) * Uu + u];
    const float k2 = kern[(size_t)(d + 2) * Uu + u];
    const float k3 = kern[(size_t)(d + 3) * Uu + u];
    #pragma unroll
    for (int r = 0; r < 8; ++r){
      const f32x4 f4 = *(const f32x4*)&fS[g * 8 + r][d];
      zz[r] = fmaf(f4.x, k0, fmaf(f4.y, k1, fmaf(f4.z, k2, fmaf(f4.w, k3, zz[r]))));
    }
  }
  // waves 0,1 hold g=0 (rows 0-7); waves 2,3 hold g=1 (rows 8-15)
  #pragma unroll
  for (int r = 0; r < 8; ++r){
    float v = waveSum(zz[r] * zz[r]);
    if ((t & 63) == 0) red[t >> 6][r] = v;
  }
  __syncthreads();
  float scl[8];
  #pragma unroll
  for (int r = 0; r < 8; ++r){
    const float ns  = (g == 0) ? (red[0][r] + red[1][r]) : (red[2][r] + red[3][r]);
    const float nrm = fmaxf(sqrtf(ns), 1e-15f);
    const float th  = tanhf(nrm);
    scl[r] = th / nrm;
    xh[(size_t)(n0 + g * 8 + r) * Uu + u] = f2bf(zz[r] * scl[r]);
  }
  // v4 element (u, jw=4*q4w+e) at short-offset uc*256 + q4w*64 + l15*4 + e;
  // this thread owns jw = g*8 .. g*8+7 -> q4w = 2g + {0,1}
  {
    short* vt = v4 + (size_t)blockIdx.x * 2048 + (size_t)(u >> 4) * 256 + (u & 15) * 4;
    #pragma unroll
    for (int qq = 0; qq < 2; ++qq){
      s16x4 w;
      #pragma unroll
      for (int e = 0; e < 4; ++e) w[e] = f2bf(zz[qq * 4 + e] * scl[qq * 4 + e]);
      *(s16x4*)(vt + (g * 2 + qq) * 64) = w;
    }
  }
  if (t < 16){
    const float ns  = (t < 8) ? (red[0][t] + red[1][t]) : (red[2][t - 8] + red[3][t - 8]);
    const float nrm = fmaxf(sqrtf(ns), 1e-15f);
    const float th  = tanhf(nrm);
    x2[n0 + t] = th * th;
  }
  if (blockIdx.x == 0){
    const float bv = (t < 128) ? bias[t] : 0.f;
    float v = waveSum(bv * bv);
    if ((t & 63) == 0) redb[t >> 6] = v;
    __syncthreads();
    const float n2  = redb[0] + redb[1] + redb[2] + redb[3];
    const float nrm = fmaxf(sqrtf(n2), 1e-15f);
    const float th  = tanhf(nrm);
    if (t < 128) bb[t] = bv * th / nrm;
    if (t == 0) bb[Uu] = th * th;
  }
}

// LDS-shared attention, doubled-i waves: each wave owns 32 i-rows (two 16-row
// Q groups) so every kf/vf LDS read feeds TWO groups' MFMAs -> LDS bytes per
// unit of work HALVED (the co-binding resource per R7/R8 accounting; VALU is
// the other and is work-proportional). Same layouts/protocol as R8 (proven):
// per-iter vmem order [4x gl_lds stage(t+1)][4x adj int4 (t+1)], vmcnt(4)
// pre-barrier leaves the adj loads in flight one full iteration.
__global__ __launch_bounds__(256, 2) void k_attn(const int* __restrict__ adj,
                                                 const short* __restrict__ xh,
                                                 const short* __restrict__ v4,
                                                 const float* __restrict__ x2g,
                                                 float* __restrict__ Opart,
                                                 float* __restrict__ lpart){
  const int t    = threadIdx.x;
  const int lane = t & 63;
  const int wid  = t >> 6;
  const int l15  = lane & 15;
  const int q4   = lane >> 4;
  const int ig   = blockIdx.x >> 4;           // 64 i-groups of 128 rows
  const int jc   = blockIdx.x & 15;           // j-chunk shared by the 4 waves
  const int i0   = ig * 128 + wid * 32;       // this wave: rows i0 .. i0+31
  const int jbase = jc * JCL;

  __shared__ __align__(16) short kb[2][4096];   // K tile (2 subtiles, frag layout)
  __shared__ __align__(16) short vb[2][4096];   // V tile (2 subtiles, uc layout)
  __shared__ __align__(16) float x2S[JCL];      // x2 chunk (2KB), staged once

  // per-wave staging sources (wave wid stages chunk kk=wid / quarter wid)
  const char* ksrcW = (const char*)xh + (size_t)jbase * 256
                      + l15 * 256 + wid * 64 + q4 * 16;
  const char* vsrcW = (const char*)v4 + (size_t)(jbase >> 4) * 4096
                      + wid * 1024 + lane * 16;

  // stage tile 0 (both subtiles) + x2 chunk
  GL_LDS(ksrcW,        (char*)&kb[0][0] + wid * 1024);
  GL_LDS(ksrcW + 4096, (char*)&kb[0][0] + 4096 + wid * 1024);
  GL_LDS(vsrcW,        (char*)&vb[0][0] + wid * 1024);
  GL_LDS(vsrcW + 4096, (char*)&vb[0][0] + 4096 + wid * 1024);
  if (wid < 2)
    GL_LDS((const char*)(x2g + jbase) + wid * 1024 + lane * 16, (char*)x2S + wid * 1024);

  // Q B-frags for both 16-row groups, resident all kernel
  s16x8 qf[2][4];
  float x2i[2], Bv2j[2], nBv2[2];
  int   itDiag[2], sDiag[2];
  #pragma unroll
  for (int g = 0; g < 2; ++g){
    const int irow = i0 + g * 16 + l15;
    const short* qp = xh + (size_t)irow * Uu + q4 * 8;
    #pragma unroll
    for (int kk = 0; kk < 4; ++kk) qf[g][kk] = *(const s16x8*)(qp + kk * 32);
    const float xi = x2g[irow];
    x2i[g]  = xi;
    const float Bv = 1.f - xi;
    Bv2j[g] = Bv * Bv;
    nBv2[g] = -2.f * Bv;
    const int i0g = i0 + g * 16;
    itDiag[g] = ((i0g >> 9) == jc) ? ((i0g & 511) >> 5) : -1;
    sDiag[g]  = (i0g >> 4) & 1;
  }

  f32x4 oc[2][8];
  #pragma unroll
  for (int g = 0; g < 2; ++g)
    #pragma unroll
    for (int uc = 0; uc < 8; ++uc) oc[g][uc] = (f32x4){0.f, 0.f, 0.f, 0.f};
  float lacc[2] = {0.f, 0.f};

  // adj pointers per group; queue holds current tile's 4 int4 (2 groups x 2 subtiles)
  const int* ap0 = adj + (size_t)(i0 + l15) * Nn + jbase + q4 * 4;
  const int* ap1 = adj + (size_t)(i0 + 16 + l15) * Nn + jbase + q4 * 4;
  int4 aqC[4];
  aqC[0] = *(const int4*)(ap0);        // g0 s0
  aqC[1] = *(const int4*)(ap0 + 16);   // g0 s1
  aqC[2] = *(const int4*)(ap1);        // g1 s0
  aqC[3] = *(const int4*)(ap1 + 16);   // g1 s1

  asm volatile("s_waitcnt vmcnt(0)" ::: "memory");
  __builtin_amdgcn_s_barrier();
  __builtin_amdgcn_sched_barrier(0);

  #pragma unroll 1
  for (int it = 0; it < NIT; ++it){
    const int cur = it & 1;
    // ---- stage tile it+1 (4 gl_lds, oldest vmem ops of this iter) ----
    if (it + 1 < NIT){
      const size_t o = (size_t)(it + 1) * 8192;
      GL_LDS(ksrcW + o,        (char*)&kb[cur ^ 1][0] + wid * 1024);
      GL_LDS(ksrcW + o + 4096, (char*)&kb[cur ^ 1][0] + 4096 + wid * 1024);
      GL_LDS(vsrcW + o,        (char*)&vb[cur ^ 1][0] + wid * 1024);
      GL_LDS(vsrcW + o + 4096, (char*)&vb[cur ^ 1][0] + 4096 + wid * 1024);
    }
    __builtin_amdgcn_sched_barrier(0);
    // ---- adj loads for tile it+1 (the 4 NEWEST vmem ops; clamp at end) ----
    const int itn = (it + 1 < NIT) ? (it + 1) : (NIT - 1);
    int4 aqN[4];
    aqN[0] = *(const int4*)(ap0 + itn * 32);
    aqN[1] = *(const int4*)(ap0 + itn * 32 + 16);
    aqN[2] = *(const int4*)(ap1 + itn * 32);
    aqN[3] = *(const int4*)(ap1 + itn * 32 + 16);
    __builtin_amdgcn_sched_barrier(0);

    // ---- two serial 16-j subtiles, each feeding BOTH i-groups ----
    #pragma unroll
    for (int sdx = 0; sdx < 2; ++sdx){
      const char* kbp = (const char*)&kb[cur][0] + sdx * 4096;
      const char* vbp = (const char*)&vb[cur][0] + sdx * 4096;
      s16x8 kf[4];
      #pragma unroll
      for (int kk = 0; kk < 4; ++kk)
        kf[kk] = *(const s16x8*)(kbp + kk * 1024 + lane * 16);
      // S^T for both groups from the SAME kf
      f32x4 s0 = {0.f, 0.f, 0.f, 0.f};
      f32x4 s1 = {0.f, 0.f, 0.f, 0.f};
      #pragma unroll
      for (int kk = 0; kk < 4; ++kk){
        s0 = MFMA_K32(kf[kk], qf[0][kk], s0);
        s1 = MFMA_K32(kf[kk], qf[1][kk], s1);
      }
      const f32x4 x2j = *(const f32x4*)&x2S[it * TJ + sdx * 16 + q4 * 4];
      s16x4 vf[8];
      #pragma unroll
      for (int uc = 0; uc < 8; ++uc)
        vf[uc] = *(const s16x4*)(vbp + uc * 512 + lane * 8);

      s16x4 pbg[2];
      #pragma unroll
      for (int g = 0; g < 2; ++g){
        const f32x4 sv = g ? s1 : s0;
        const int4  aq = aqC[g * 2 + sdx];
        const int aarr[4] = {aq.x, aq.y, aq.z, aq.w};
        float pv[4];
        #pragma unroll
        for (int r = 0; r < 4; ++r){
          const float xy  = sv[r];
          const float x2v = x2j[r];
          const float Aa  = fmaf(-2.f, xy, 1.f + x2v);
          const float num = fmaf(Aa * Aa, x2i[g], fmaf(nBv2[g] * Aa, xy, Bv2j[g] * x2v));
          const float den = fmaf(x2i[g], x2v, fmaf(-2.f, xy, 1.f));
          const float sq  = __builtin_amdgcn_sqrtf(fmaxf(num, 0.f));
          const float pd  = fmaxf(den - sq, 1e-30f);
          const float p   = fminf((den + sq) * __builtin_amdgcn_rcpf(pd), 2.0e7f);
          const bool keep = (aarr[r] != 0) && (sq != 0.f);
          pv[r] = keep ? p : 0.f;
        }
        if (it == itDiag[g] && sdx == sDiag[g]){   // wave-uniform branch
          const int j0 = jbase + it * TJ + sdx * 16;
          const int irow = i0 + g * 16 + l15;
          #pragma unroll
          for (int r = 0; r < 4; ++r)
            if ((j0 + 4 * q4 + r) == irow) pv[r] = 0.f;
        }
        lacc[g] += (pv[0] + pv[1]) + (pv[2] + pv[3]);
        s16x4 pb;
        #pragma unroll
        for (int r = 0; r < 4; ++r) pb[r] = f2bf(pv[r]);
        pbg[g] = pb;
      }

      // PV: same vf A-operand feeds both groups
      #pragma unroll
      for (int uc = 0; uc < 8; ++uc){
        oc[0][uc] = mfma_k16(vf[uc], pbg[0], oc[0][uc]);
        oc[1][uc] = mfma_k16(vf[uc], pbg[1], oc[1][uc]);
      }
    }

    aqC[0] = aqN[0]; aqC[1] = aqN[1]; aqC[2] = aqN[2]; aqC[3] = aqN[3];
    // drain the 4 stage gl_lds; leave the 4 adj loads (tile it+1) in flight
    asm volatile("s_waitcnt vmcnt(4)" ::: "memory");
    __builtin_amdgcn_s_barrier();
    __builtin_amdgcn_sched_barrier(0);
  }

  // ---- epilogue: reduce l over q4, store per-chunk partials (no atomics) ----
  #pragma unroll
  for (int g = 0; g < 2; ++g){
    float la = lacc[g];
    la += __shfl_xor(la, 16);
    la += __shfl_xor(la, 32);
    if (lane < 16) lpart[(size_t)jc * Nn + i0 + g * 16 + lane] = la;
    float* op = Opart + ((size_t)jc * Nn + i0 + g * 16 + l15) * Uu + q4 * 4;
    #pragma unroll
    for (int uc = 0; uc < 8; ++uc) *(f32x4*)(op + uc * 16) = oc[g][uc];
  }
}

// epilogue: sum 16 partials, normalize, mobius matvec rescale, mobius bias add
__global__ __launch_bounds__(256) void k_out(const float* __restrict__ Opart,
                                             const float* __restrict__ lpart,
                                             const float* __restrict__ x2g,
                                             const float* __restrict__ bb,
                                             float* __restrict__ out){
  const int t  = threadIdx.x;
  const int i0 = blockIdx.x * MI;
  const int er = t >> 4;
  const int ec = t & 15;
  float l = 0.f;
  #pragma unroll
  for (int c = 0; c < NJC; ++c) l += lpart[(size_t)c * Nn + i0 + er];
  const float linv = 1.f / fmaxf(l, 1e-30f);
  float mx[8]; float s2 = 0.f;
  #pragma unroll
  for (int k = 0; k < 8; ++k){
    float v = 0.f;
    #pragma unroll
    for (int c = 0; c < NJC; ++c)
      v += Opart[((size_t)c * Nn + i0 + er) * Uu + ec + 16 * k];
    v *= linv;
    mx[k] = v; s2 = fmaf(v, v, s2);
  }
  s2 += __shfl_xor(s2, 1); s2 += __shfl_xor(s2, 2);
  s2 += __shfl_xor(s2, 4); s2 += __shfl_xor(s2, 8);
  const float mx_n = fmaxf(sqrtf(s2), 1e-15f);
  const float x2e  = x2g[i0 + er];
  const float x_n  = fmaxf(sqrtf(x2e), 1e-15f);
  const float xcl  = fminf(x_n, 1.f - 1e-7f);
  const float art  = 0.5f * __logf((1.f + xcl) / (1.f - xcl));
  const float th   = tanhf(mx_n / x_n * art);
  const float rmn  = th / mx_n;
  float o[8], bu[8]; float ob = 0.f;
  #pragma unroll
  for (int k = 0; k < 8; ++k){
    bu[k] = bb[ec + 16 * k];
    o[k]  = mx[k] * rmn;
    ob = fmaf(o[k], bu[k], ob);
  }
  ob += __shfl_xor(ob, 1); ob += __shfl_xor(ob, 2);
  ob += __shfl_xor(ob, 4); ob += __shfl_xor(ob, 8);
  const float o2   = th * th;
  const float b2   = bb[Uu];
  const float cnum = 1.f + 2.f * ob + b2;
  const float cden = fmaf(o2, b2, 1.f + 2.f * ob);
  const float rden = 1.f / fmaxf(cden, 1e-15f);
  const float co   = 1.f - o2;
  #pragma unroll
  for (int k = 0; k < 8; ++k)
    out[(size_t)(i0 + er) * Uu + ec + 16 * k] = (cnum * o[k] + co * bu[k]) * rden;
}

extern "C" void kernel_launch(void* const* d_in, const int* in_sizes, int n_in,
                              void* d_out, int out_size, void* d_ws, size_t ws_size,
                              hipStream_t stream){
  (void)in_sizes; (void)n_in; (void)out_size; (void)ws_size;
  const float* feat = (const float*)d_in[0];
  const int*   adj  = (const int*)d_in[1];
  const float* kern = (const float*)d_in[2];
  const float* bias = (const float*)d_in[3];

  float* Opart = (float*)d_ws;                          // [16][N][U] f32, 64 MB
  float* lpart = Opart + (size_t)NJC * Nn * Uu;         // [16][N]
  float* x2    = lpart + (size_t)NJC * Nn;              // [N]
  float* bbw   = x2 + Nn;                               // [U+1] (padded to 132)
  short* xh    = (short*)(bbw + 132);                   // [N][U] bf16, 2 MB
  short* v4    = xh + (size_t)Nn * Uu;                  // [N/16][2048] bf16, 2 MB

  k_prep<<<Nn / 16, 256, 0, stream>>>(feat, kern, bias, xh, v4, x2, bbw);
  k_attn<<<(Nn / 128) * NJC, 256, 0, stream>>>(adj, xh, v4, x2, Opart, lpart);
  k_out <<<Nn / MI, 256, 0, stream>>>(Opart, lpart, x2, bbw, (float*)d_out);
}